// Round 19
// baseline (148.274 us; speedup 1.0000x reference)
//
#include <hip/hip_runtime.h>
#include <hip/hip_bf16.h>
#include <math.h>

#define B_ 32
#define E_ 16384
#define N_ 1000
#define D_ 128
#define NN_ (N_ * N_)
#define T_ 8   // 128-edge sub-tiles per block (8 waves x 16 edges); grid = 512 = 2/CU
#define OUT_U4 8000000   // d_out in uint4 units: 32e6 floats = 128,000,000 B / 16

typedef __attribute__((ext_vector_type(8))) short bf16x8;
typedef __attribute__((ext_vector_type(4))) float f32x4;

// fp32 -> bf16 RNE (scalar; finite inputs)
__device__ __forceinline__ unsigned short f2bf(float f) {
    unsigned u = __float_as_uint(f);
    u += 0x7FFFu + ((u >> 16) & 1u);
    return (unsigned short)(u >> 16);
}

// packed pair fp32 -> bf16x2 (v_cvt_pk_bf16_f32)
__device__ __forceinline__ unsigned pk2(float lo, float hi) {
    __hip_bfloat162 h = __float22bfloat162_rn(make_float2(lo, hi));
    return *(unsigned*)&h;
}

__device__ __forceinline__ f32x4 mfma16(bf16x8 a, bf16x8 b, f32x4 c) {
    return __builtin_amdgcn_mfma_f32_16x16x32_bf16(a, b, c, 0, 0, 0);
}

__device__ __forceinline__ float silu_(float z) {
    return z * __builtin_amdgcn_rcpf(1.0f + __expf(-z));
}

// decode 17-bit quantized cell payload (call only when bit31 set; q >= 1)
__device__ __forceinline__ float dec17(unsigned x) {
    return (float)((x & 0x1FFFFu) - 1u) * (10.0f / 131070.0f);
}

// async global->LDS, 16B per lane (dest = wave-uniform base + lane*16)
__device__ __forceinline__ void gload_lds16(const void* g, void* l) {
    __builtin_amdgcn_global_load_lds(
        (const __attribute__((address_space(1))) unsigned*)g,
        (__attribute__((address_space(3))) unsigned*)l, 16, 0, 0);
}

// Pre-swizzle W1,W2 (128x128 fp32) -> bf16 at byte row*256 + ((2*pos)^((row&7)<<4)).
// W1: pos = src column (natural).  W2: COLUMN-PERMUTED so GEMM1's C-fragment
// feeds GEMM2 directly with NO transpose: k-slot pos = q*32 + g*8 + nn*4 + r
// holds logical f1 = (q*2+nn)*16 + g*4 + r (where GEMM1's output lands).
__global__ void prep_weights(const float* __restrict__ W1,
                             const float* __restrict__ W2,
                             unsigned short* __restrict__ wsz) {
    int t = blockIdx.x * 256 + threadIdx.x;   // 0..32767
    int w = t >> 14, e = t & 16383;
    int row = e >> 7, pos = e & 127;
    int src_col = pos;
    if (w) {
        int q = pos >> 5, gg = (pos >> 3) & 3, nn = (pos >> 2) & 1, r = pos & 3;
        src_col = (q * 2 + nn) * 16 + gg * 4 + r;
    }
    float v = (w ? W2 : W1)[row * 128 + src_col];
    char* dst = (char*)wsz + (size_t)w * 32768 + row * 256 + ((pos * 2) ^ ((row & 7) << 4));
    *(unsigned short*)dst = f2bf(v);
}

// K1: MLP compute + interleaved zero-fill of the output.
// FILL IS BOUNDS-GUARDED grid-stride: idx = (st*4+i)*262144 + bid*512 + tid,
// guarded by idx < OUT_U4. (R17/R18 aborted on an unguarded 128MiB fill into
// a 125.8MiB buffer — MB/MiB confusion, 6.2MB OOB.)
// Per-edge values go to the compact ev array; scatter deferred to K2 (stream
// order guarantees fills complete first).
// (512,2): 16 waves/CU, 128-VGPR cap; phase-split body fits (R10 proven).
__global__ __launch_bounds__(512, 2) void mlp_fill_kernel(
    const float* __restrict__ X,
    const unsigned short* __restrict__ wsz,
    const float* __restrict__ b1, const float* __restrict__ b2,
    const float* __restrict__ Wo, const float* __restrict__ bo,
    float* __restrict__ ev, uint4* __restrict__ outfill)
{
    __shared__ __align__(16) char Wb[65536];   // W1 | W2 bf16, swizzled
    __shared__ __align__(16) float BiasL[388]; // b1 | b2 | Wo | bo (fp32)

    const int tid = threadIdx.x;
    const int lane = tid & 63;
    const int wv = tid >> 6;          // wave 0..7, owns 16 edges per sub-tile
    const int l15 = lane & 15;
    const int g = (lane >> 4) & 3;

    const int bb = blockIdx.x >> 4;                 // batch (16 blocks per batch)
    const int e0 = (blockIdx.x & 15) * (128 * T_);  // 1024 edges per block

    if (tid < 96) {
        const float* src = tid < 32 ? b1 : (tid < 64 ? b2 : Wo);
        ((f32x4*)BiasL)[tid] = ((const f32x4*)src)[tid & 31];
    }
    if (tid == 96) BiasL[384] = bo[0];

    // stage both weight matrices: 64KB linear, zero VALU
    #pragma unroll
    for (int it = 0; it < 8; ++it) {
        int off = it * 8192 + tid * 16;
        gload_lds16((const char*)wsz + off, (char*)Wb + off);
    }
    __syncthreads();
    const float bo0 = BiasL[384];

    const uint4 z4 = make_uint4(0u, 0u, 0u, 0u);
    const int fillbase = blockIdx.x * 512 + tid;

    #pragma unroll 1   // runtime loop: keeps per-iteration liveness bounded
    for (int st = 0; st < T_; ++st) {
        const int eb0 = e0 + st * 128 + wv * 16;

        // ---- load X for this wave's 16 edges (16 regs live) ----
        bf16x8 a[4];
        {
            const float* p0 = X + ((size_t)bb * E_ + eb0 + l15) * D_ + g * 8;
            #pragma unroll
            for (int ks = 0; ks < 4; ++ks) {
                float4 u0 = *(const float4*)(p0 + ks * 32);
                float4 u1 = *(const float4*)(p0 + ks * 32 + 4);
                bf16x8 t; unsigned* tu = (unsigned*)&t;
                tu[0] = pk2(u0.x, u0.y); tu[1] = pk2(u0.z, u0.w);
                tu[2] = pk2(u1.x, u1.y); tu[3] = pk2(u1.z, u1.w);
                a[ks] = t;
            }
        }

        // interleaved fill: 4 guarded coalesced uint4 stores, fire-and-forget
        #pragma unroll
        for (int i = 0; i < 4; ++i) {
            int idx = (st * 4 + i) * 262144 + fillbase;   // 262144 = 512 blk * 512 thr
            if (idx < OUT_U4) outfill[idx] = z4;
        }

        // ---- PHASE 1: all GEMM1 quarters -> pa[4] (a dies at phase end) ----
        bf16x8 pa[4];
        #pragma unroll
        for (int q = 0; q < 4; ++q) {
            f32x4 acc1[2];
            acc1[0] = (f32x4){0.f, 0.f, 0.f, 0.f};
            acc1[1] = (f32x4){0.f, 0.f, 0.f, 0.f};

            #pragma unroll
            for (int ks = 0; ks < 4; ++ks)
                #pragma unroll
                for (int nn = 0; nn < 2; ++nn) {
                    int row = l15 + (q * 2 + nn) * 16;
                    bf16x8 aw = *(const bf16x8*)(Wb + row * 256 +
                                  ((ks * 64 + g * 16) ^ ((row & 7) << 4)));
                    acc1[nn] = mfma16(aw, a[ks], acc1[nn]);
                }

            // h fragment in-register: k-slot (g, nn*4+r) = acc1[nn][r]
            f32x4 b1q0 = ((f32x4*)BiasL)[(q * 2 + 0) * 4 + g];
            f32x4 b1q1 = ((f32x4*)BiasL)[(q * 2 + 1) * 4 + g];
            unsigned* au = (unsigned*)&pa[q];
            au[0] = pk2(silu_(acc1[0][0] + b1q0[0]), silu_(acc1[0][1] + b1q0[1]));
            au[1] = pk2(silu_(acc1[0][2] + b1q0[2]), silu_(acc1[0][3] + b1q0[3]));
            au[2] = pk2(silu_(acc1[1][0] + b1q1[0]), silu_(acc1[1][1] + b1q1[1]));
            au[3] = pk2(silu_(acc1[1][2] + b1q1[2]), silu_(acc1[1][3] + b1q1[3]));
            __builtin_amdgcn_sched_barrier(0);   // no cross-q hoisting
        }

        // ---- PHASE 2: GEMM2, q-major; acc2 born after a died ----
        f32x4 acc2[8];
        #pragma unroll
        for (int n = 0; n < 8; ++n)
            acc2[n] = (f32x4){0.f, 0.f, 0.f, 0.f};

        #pragma unroll
        for (int q = 0; q < 4; ++q) {
            #pragma unroll
            for (int n = 0; n < 8; ++n) {
                int row = l15 + n * 16;
                bf16x8 w2 = *(const bf16x8*)(Wb + 32768 + row * 256 +
                              ((q * 64 + g * 16) ^ ((row & 7) << 4)));
                acc2[n] = mfma16(w2, pa[q], acc2[n]);
            }
            __builtin_amdgcn_sched_barrier(0);   // cap ds-read transients per q
        }

        // ---- epilogue: lane holds f2 = n*16+g*4+r for edge eb0+l15 ----
        float zed = 0.f;
        #pragma unroll
        for (int n = 0; n < 8; ++n) {
            f32x4 b2q = ((f32x4*)BiasL)[32 + n * 4 + g];
            f32x4 woq = ((f32x4*)BiasL)[64 + n * 4 + g];
            zed += silu_(acc2[n][0] + b2q[0]) * woq[0];
            zed += silu_(acc2[n][1] + b2q[1]) * woq[1];
            zed += silu_(acc2[n][2] + b2q[2]) * woq[2];
            zed += silu_(acc2[n][3] + b2q[3]) * woq[3];
        }
        zed += __shfl_xor(zed, 16, 64);
        zed += __shfl_xor(zed, 32, 64);

        // sigmoid*10 -> compact ev array (coalesced 16-float store per wave)
        if (g == 0) {
            float z = zed + bo0;
            ev[(size_t)bb * E_ + eb0 + l15] =
                10.0f * __builtin_amdgcn_rcpf(1.0f + __expf(-z));
        }
    }
}

// K2: packed atomicMax scatter (last-e-wins on duplicates). Runs after K1,
// so all zero-fills are complete (stream order).
__global__ __launch_bounds__(256) void scatter_packed(
    const int* __restrict__ EI, const float* __restrict__ ev,
    unsigned* __restrict__ out)
{
    int i = blockIdx.x * 256 + threadIdx.x;   // 0..B*E-1
    int b = i >> 14, e = i & 16383;
    int s = EI[(size_t)b * 2 * E_ + e];
    int d = EI[(size_t)b * 2 * E_ + E_ + e];
    float val = ev[i];
    unsigned qv = (unsigned)(val * 13107.0f + 0.5f) + 1u;  // 131070/10
    if (qv > 0x1FFFFu) qv = 0x1FFFFu;
    unsigned packed = 0x80000000u | ((unsigned)e << 17) | qv;
    atomicMax(out + ((size_t)b * NN_ + (size_t)s * N_ + d), packed);
}

// K3: fused finalize. Cell states: 0 = empty (final 0.0f); bit31 set = packed
// quantized edge value; bit31 clear & nonzero = already-final float in (0,10].
// Every writer of a cell writes the same v, so concurrent/stale reads are
// benign: a stale read sees the packed form and recomputes the identical v.
__global__ __launch_bounds__(256) void finalize_fused(
    const int* __restrict__ EI, unsigned* __restrict__ out)
{
    int i = blockIdx.x * 256 + threadIdx.x;   // 0..B*E-1
    int b = i >> 14, e = i & 16383;
    int s = EI[(size_t)b * 2 * E_ + e];
    int d = EI[(size_t)b * 2 * E_ + E_ + e];
    unsigned* ob = out + (size_t)b * NN_;
    unsigned x1 = ob[(size_t)s * N_ + d];
    unsigned x2 = ob[(size_t)d * N_ + s];
    float v;
    if (!(x1 >> 31) && x1)      v = __uint_as_float(x1);   // already final
    else if (!(x2 >> 31) && x2) v = __uint_as_float(x2);   // already final
    else {
        float c1 = (x1 >> 31) ? dec17(x1) : 0.0f;
        float c2 = (x2 >> 31) ? dec17(x2) : 0.0f;
        v = 0.5f * (c1 + c2);
    }
    unsigned uv = __float_as_uint(v);
    ob[(size_t)s * N_ + d] = uv;
    ob[(size_t)d * N_ + s] = uv;
}

extern "C" void kernel_launch(void* const* d_in, const int* in_sizes, int n_in,
                              void* d_out, int out_size, void* d_ws, size_t ws_size,
                              hipStream_t stream) {
    const float* X  = (const float*)d_in[0];
    const int*   EI = (const int*)d_in[1];
    const float* W1 = (const float*)d_in[2];
    const float* b1 = (const float*)d_in[3];
    const float* W2 = (const float*)d_in[4];
    const float* b2 = (const float*)d_in[5];
    const float* Wo = (const float*)d_in[6];
    const float* bo = (const float*)d_in[7];
    unsigned* out = (unsigned*)d_out;
    unsigned short* wsz = (unsigned short*)d_ws;           // 64KB swizzled weights
    float* ev = (float*)((char*)d_ws + 65536);             // 2MB per-edge values

    prep_weights<<<dim3(128), dim3(256), 0, stream>>>(W1, W2, wsz);
    mlp_fill_kernel<<<dim3((B_ * E_) / (128 * T_)), dim3(512), 0, stream>>>(
        X, wsz, b1, b2, Wo, bo, ev, (uint4*)d_out);
    scatter_packed<<<dim3((B_ * E_) / 256), dim3(256), 0, stream>>>(EI, ev, out);
    finalize_fused<<<dim3((B_ * E_) / 256), dim3(256), 0, stream>>>(EI, out);
}